// Round 1
// 689.085 us; speedup vs baseline: 1.1903x; 1.1903x over previous
//
#include <hip/hip_runtime.h>
#include <hip/hip_bf16.h>

#define NUM_OPS   100000
#define NUM_MACH  512
#define HDIM      128
#define P1        100352            // m2o key offset (98*1024)
#define NHIST     200704            // 196*1024 == 784*256 combined key space
#define NBLK      196               // hist scan blocks (1024 elems each)
#define NCOARSE   784               // coarse buckets (key >> 8)
#define NBC       256               // blocks for coarse hist/fill passes
#define NBM       256               // counting-sort blocks for machine buckets
#define MHWORDS   (NUM_MACH * NBM)  // 131072 = 128*1024
#define NBLK_M    128               // blockhist scan blocks

typedef short short8 __attribute__((ext_vector_type(8)));
typedef float floatx4 __attribute__((ext_vector_type(4)));

__device__ __forceinline__ unsigned short f2bf(float f) {
    unsigned u = __float_as_uint(f);
    unsigned r = (u + 0x7FFFu + ((u >> 16) & 1u)) >> 16;   // RNE
    return (unsigned short)r;
}

// ---------------- embedding: out[r,h] = sum_f F[r,f]*W[h,f] + b[h] ----------------
__global__ void k_embed(const float* __restrict__ F,
                        const float* __restrict__ W,
                        const float* __restrict__ b,
                        float* __restrict__ out, int M, int FD) {
    int idx = blockIdx.x * blockDim.x + threadIdx.x;
    if (idx >= M * HDIM) return;
    int r = idx >> 7, h = idx & 127;
    const float* f = F + (size_t)r * FD;
    const float* w = W + (size_t)h * FD;
    float s = b[h];
    for (int i = 0; i < FD; ++i) s += f[i] * w[i];
    out[idx] = s;
}

// ---------------- weight convert: Wb[l][h][0:256] = bf16(Wp[l][h] || Wc[l][h]) ----------------
__global__ void k_wconv(const float* __restrict__ Wp, const float* __restrict__ Wc,
                        unsigned short* __restrict__ Wb) {
    int i = blockIdx.x * blockDim.x + threadIdx.x;
    if (i >= 2 * 128 * 256) return;
    int l = i >> 15, h = (i >> 8) & 127, k = i & 255;
    float v = (k < 128) ? Wp[(size_t)l * 16384 + h * 128 + k]
                        : Wc[(size_t)l * 16384 + h * 128 + (k - 128)];
    Wb[i] = f2bf(v);
}

// ---------------- coarse pass A: per-block LDS histograms over key>>8 ----------------
// key space: prec targets at [0,NUM_OPS), m2o targets at [P1, P1+NUM_OPS)
__global__ __launch_bounds__(256) void k_chist(const int* __restrict__ prec_e, int nprec,
                                               const int* __restrict__ comp_e, int E,
                                               int* __restrict__ blockhist) {
    __shared__ int h[NCOARSE];
    for (int i = threadIdx.x; i < NCOARSE; i += 256) h[i] = 0;
    __syncthreads();
    int NT = nprec + E;
    int ch = (NT + NBC - 1) / NBC;
    int i0 = blockIdx.x * ch, i1 = min(NT, i0 + ch);
    for (int i = i0 + threadIdx.x; i < i1; i += 256) {
        int key = (i < nprec) ? prec_e[nprec + i] : (P1 + comp_e[i - nprec]);
        atomicAdd(&h[key >> 8], 1);
    }
    __syncthreads();
    for (int i = threadIdx.x; i < NCOARSE; i += 256)
        blockhist[i * NBC + blockIdx.x] = h[i];
}

// ---------------- coarse pass B: place packed (val<<8 | key&255) via LDS cursors ----------------
__global__ __launch_bounds__(256) void k_cfill(const int* __restrict__ prec_e, int nprec,
                                               const int* __restrict__ comp_e, int E, int M,
                                               const int* __restrict__ scan,
                                               int* __restrict__ pairs) {
    __shared__ int cur[NCOARSE];
    for (int i = threadIdx.x; i < NCOARSE; i += 256) cur[i] = scan[i * NBC + blockIdx.x];
    __syncthreads();
    int NT = nprec + E;
    int ch = (NT + NBC - 1) / NBC;
    int i0 = blockIdx.x * ch, i1 = min(NT, i0 + ch);
    for (int i = i0 + threadIdx.x; i < i1; i += 256) {
        int key, val;
        if (i < nprec) { key = prec_e[nprec + i]; val = prec_e[i]; }
        else { int e = i - nprec; key = P1 + comp_e[e]; val = comp_e[E + e] - M; }
        int pos = atomicAdd(&cur[key >> 8], 1);
        pairs[pos] = (val << 8) | (key & 255);
    }
}

// ---------------- fine pass: per-coarse-bucket counting sort (256 keys, LDS) ----------------
// writes rs[key] for all 256 keys of the bucket + scatters values into bucket_all
__global__ __launch_bounds__(256) void k_fine(const int* __restrict__ scan,
                                              const int* __restrict__ pairs, int NT,
                                              int* __restrict__ rs,
                                              int* __restrict__ bucket_all) {
    __shared__ int hh[256];
    __shared__ int ex[256];
    __shared__ int cu[256];
    int b = blockIdx.x, t = threadIdx.x;
    int s = scan[b * NBC];
    int e = (b == NCOARSE - 1) ? NT : scan[(b + 1) * NBC];
    hh[t] = 0;
    __syncthreads();
    for (int i = s + t; i < e; i += 256) atomicAdd(&hh[pairs[i] & 255], 1);
    __syncthreads();
    int v = hh[t];
    ex[t] = v; __syncthreads();
    for (int o = 1; o < 256; o <<= 1) {
        int x = (t >= o) ? ex[t - o] : 0; __syncthreads();
        ex[t] += x; __syncthreads();
    }
    int start = s + ex[t] - v;      // exclusive offset for key b*256+t
    rs[b * 256 + t] = start;
    cu[t] = start;
    __syncthreads();
    for (int i = s + t; i < e; i += 256) {
        int p = pairs[i];
        int pos = atomicAdd(&cu[p & 255], 1);
        bucket_all[pos] = ((unsigned)p) >> 8;
    }
}

// ---------------- machine counting-sort pass A: per-block LDS histograms ----------------
__global__ __launch_bounds__(256) void k_mhist(const int* __restrict__ comp_e, int E, int M,
                                               int* __restrict__ blockhist) {
    __shared__ int h[NUM_MACH];
    for (int i = threadIdx.x; i < NUM_MACH; i += 256) h[i] = 0;
    __syncthreads();
    int blk = blockIdx.x;
    int ch = (E + NBM - 1) / NBM;
    int e0 = blk * ch, e1 = min(E, e0 + ch);
    for (int e = e0 + threadIdx.x; e < e1; e += 256)
        atomicAdd(&h[comp_e[E + e] - M], 1);
    __syncthreads();
    for (int i = threadIdx.x; i < NUM_MACH; i += 256)
        blockhist[i * NBM + blk] = h[i];
}

// ---------------- scan phase 1: per-block sums (1024 ints / block) ----------------
__global__ __launch_bounds__(256) void k_blocksum(const int* __restrict__ arr, int* __restrict__ partial) {
    __shared__ int sh[256];
    int b = blockIdx.x, t = threadIdx.x;
    int4 v = *(const int4*)(arr + b * 1024 + t * 4);
    sh[t] = v.x + v.y + v.z + v.w;
    __syncthreads();
    for (int o = 128; o; o >>= 1) { if (t < o) sh[t] += sh[t + o]; __syncthreads(); }
    if (!t) partial[b] = sh[0];
}

// ---------------- scan phase 2: exclusive scan of <=256 partials, single block ----------------
__global__ __launch_bounds__(256) void k_scanpart(const int* __restrict__ partial, int n,
                                                  int* __restrict__ block_off) {
    __shared__ int sh[256];
    int t = threadIdx.x;
    int v = (t < n) ? partial[t] : 0;
    sh[t] = v; __syncthreads();
    for (int o = 1; o < 256; o <<= 1) {
        int x = (t >= o) ? sh[t - o] : 0; __syncthreads();
        sh[t] += x; __syncthreads();
    }
    if (t < n) block_off[t] = sh[t] - v;
}

// ---------------- scan phase 3: write exclusive offsets (+ optional cursor copy) ----------------
__global__ __launch_bounds__(256) void k_scanwrite(const int* __restrict__ arr,
                                                   const int* __restrict__ block_off,
                                                   int* __restrict__ rs, int* __restrict__ cur) {
    __shared__ int sh[256];
    int b = blockIdx.x, t = threadIdx.x;
    int base_i = b * 1024 + t * 4;
    int4 v = *(const int4*)(arr + base_i);
    int tsum = v.x + v.y + v.z + v.w;
    sh[t] = tsum; __syncthreads();
    for (int o = 1; o < 256; o <<= 1) {
        int x = (t >= o) ? sh[t - o] : 0; __syncthreads();
        sh[t] += x; __syncthreads();
    }
    int off = block_off[b] + sh[t] - tsum;
    int4 r; r.x = off; r.y = off + v.x; r.z = off + v.x + v.y; r.w = off + v.x + v.y + v.z;
    *(int4*)(rs + base_i) = r;
    if (cur) *(int4*)(cur + base_i) = r;
}

// ---------------- extract machine row starts from scanned blockhist column 0 ----------------
__global__ void k_machrs(const int* __restrict__ moff, int* __restrict__ mach_rs, int E) {
    int t = threadIdx.x;
    for (int m = t; m < NUM_MACH; m += 256) mach_rs[m] = moff[m * NBM];
    if (t == 0) mach_rs[NUM_MACH] = E;
}

// ---------------- machine counting-sort pass B: placement via LDS cursors ----------------
__global__ __launch_bounds__(256) void k_fill_mach(const int* __restrict__ comp_e, int E, int M,
                                                   const int* __restrict__ moff,
                                                   int* __restrict__ bucket_mach) {
    __shared__ int cur[NUM_MACH];
    int blk = blockIdx.x;
    for (int i = threadIdx.x; i < NUM_MACH; i += 256) cur[i] = moff[i * NBM + blk];
    __syncthreads();
    int ch = (E + NBM - 1) / NBM;
    int e0 = blk * ch, e1 = min(E, e0 + ch);
    for (int e = e0 + threadIdx.x; e < e1; e += 256) {
        int m = comp_e[E + e] - M;
        int op = comp_e[e];
        int pos = atomicAdd(&cur[m], 1);
        bucket_mach[pos] = op;
    }
}

// ---------------- op aggregation (ILP gathers) -> bf16 A ----------------
__global__ __launch_bounds__(256) void k_agg_op(
    const float* __restrict__ op_emb, const float* __restrict__ mach_emb,
    const int* __restrict__ rs, const int* __restrict__ bucket_all,
    unsigned short* __restrict__ Ab, int* __restrict__ flags, int M) {
    int wave = threadIdx.x >> 6, lane = threadIdx.x & 63;
    int r = blockIdx.x * 4 + wave;
    if (r >= M) return;
    int h = lane * 2;

    float a0 = 0.f, a1 = 0.f;
    int s0 = rs[r], e0 = rs[r + 1];
    for (int base = s0; base < e0; base += 64) {
        int cnt = min(64, e0 - base);
        int idx = (lane < cnt) ? bucket_all[base + lane] : 0;
        for (int j = 0; j < cnt; j += 4) {
            int i0 = __shfl(idx, j);
            int i1 = __shfl(idx, j + 1);
            int i2 = __shfl(idx, j + 2);
            int i3 = __shfl(idx, j + 3);
            float2 v0 = *(const float2*)(op_emb + (size_t)i0 * HDIM + h);
            float2 v1 = *(const float2*)(op_emb + (size_t)i1 * HDIM + h);
            float2 v2 = *(const float2*)(op_emb + (size_t)i2 * HDIM + h);
            float2 v3 = *(const float2*)(op_emb + (size_t)i3 * HDIM + h);
            a0 += v0.x; a1 += v0.y;
            if (j + 1 < cnt) { a0 += v1.x; a1 += v1.y; }
            if (j + 2 < cnt) { a0 += v2.x; a1 += v2.y; }
            if (j + 3 < cnt) { a0 += v3.x; a1 += v3.y; }
        }
    }
    float pinv = 1.f / fmaxf((float)(e0 - s0), 1.f);

    float b0 = 0.f, b1 = 0.f;
    int s1 = rs[P1 + r], e1 = rs[P1 + r + 1];
    for (int base = s1; base < e1; base += 64) {
        int cnt = min(64, e1 - base);
        int idx = (lane < cnt) ? bucket_all[base + lane] : 0;
        for (int j = 0; j < cnt; j += 4) {
            int i0 = __shfl(idx, j);
            int i1 = __shfl(idx, j + 1);
            int i2 = __shfl(idx, j + 2);
            int i3 = __shfl(idx, j + 3);
            float2 v0 = *(const float2*)(mach_emb + (size_t)i0 * HDIM + h);
            float2 v1 = *(const float2*)(mach_emb + (size_t)i1 * HDIM + h);
            float2 v2 = *(const float2*)(mach_emb + (size_t)i2 * HDIM + h);
            float2 v3 = *(const float2*)(mach_emb + (size_t)i3 * HDIM + h);
            b0 += v0.x; b1 += v0.y;
            if (j + 1 < cnt) { b0 += v1.x; b1 += v1.y; }
            if (j + 2 < cnt) { b0 += v2.x; b1 += v2.y; }
            if (j + 3 < cnt) { b0 += v3.x; b1 += v3.y; }
        }
    }
    float cinv = 1.f / fmaxf((float)(e1 - s1), 1.f);

    ushort2 pa, pb;
    pa.x = f2bf(a0 * pinv); pa.y = f2bf(a1 * pinv);
    pb.x = f2bf(b0 * cinv); pb.y = f2bf(b1 * cinv);
    *(ushort2*)(Ab + (size_t)r * 256 + h)       = pa;
    *(ushort2*)(Ab + (size_t)r * 256 + 128 + h) = pb;
    if (lane == 0) flags[r] = (e0 > s0 ? 1 : 0) | (e1 > s1 ? 2 : 0);
}

// ---------------- MFMA GEMM + residual + bias-flags + LayerNorm ----------------
// out[r] = LN(emb[r] + A[r,0:256]@Wb^T + fp*bp + fc*bc)
// A-operand layout: A[m=lane&15][k=quad*8+j]; C/D: row=quad*4+reg, col=lane&15.
__global__ __launch_bounds__(256) void k_gemm_mfma(
    const unsigned short* __restrict__ Ab, const float* __restrict__ emb,
    const unsigned short* __restrict__ Wb,
    const float* __restrict__ bp, const float* __restrict__ bc,
    const int* __restrict__ flags,
    const float* __restrict__ g, const float* __restrict__ bt,
    float* __restrict__ dst, int M) {
    int wave = threadIdx.x >> 6, lane = threadIdx.x & 63;
    int m0 = blockIdx.x * 64 + wave * 16;
    if (m0 >= M) return;
    int quad = lane >> 4, col = lane & 15;

    floatx4 acc[8];
#pragma unroll
    for (int t = 0; t < 8; ++t) acc[t] = (floatx4){0.f, 0.f, 0.f, 0.f};

    const short* Arow  = (const short*)(Ab + (size_t)(m0 + col) * 256);
    const short* Wbase = (const short*)Wb;

#pragma unroll
    for (int ks = 0; ks < 8; ++ks) {
        short8 a = *(const short8*)(Arow + ks * 32 + quad * 8);
#pragma unroll
        for (int t = 0; t < 8; ++t) {
            short8 b = *(const short8*)(Wbase + (size_t)(t * 16 + col) * 256 + ks * 32 + quad * 8);
            acc[t] = __builtin_amdgcn_mfma_f32_16x16x32_bf16(a, b, acc[t], 0, 0, 0);
        }
    }

    float bpv[8], bcv[8], gv[8], btv[8];
#pragma unroll
    for (int t = 0; t < 8; ++t) {
        int c = t * 16 + col;
        bpv[t] = bp[c]; bcv[t] = bc[c]; gv[t] = g[c]; btv[t] = bt[c];
    }
#pragma unroll
    for (int reg = 0; reg < 4; ++reg) {
        int r = m0 + quad * 4 + reg;
        int fl = flags[r];
        float fp = (fl & 1) ? 1.f : 0.f, fc = (fl & 2) ? 1.f : 0.f;
        float x[8]; float s = 0.f, q = 0.f;
#pragma unroll
        for (int t = 0; t < 8; ++t) {
            float v = acc[t][reg] + emb[(size_t)r * HDIM + t * 16 + col] + fp * bpv[t] + fc * bcv[t];
            x[t] = v; s += v; q += v * v;
        }
#pragma unroll
        for (int msk = 1; msk < 16; msk <<= 1) { s += __shfl_xor(s, msk); q += __shfl_xor(q, msk); }
        float mu = s * (1.f / 128.f);
        float rstd = rsqrtf(fmaxf(q * (1.f / 128.f) - mu * mu, 0.f) + 1e-5f);
#pragma unroll
        for (int t = 0; t < 8; ++t)
            dst[(size_t)r * HDIM + t * 16 + col] = (x[t] - mu) * rstd * gv[t] + btv[t];
    }
}

// ---------------- machine gather, ILP version: wave-pair owns 64-edge batch ----------------
__global__ __launch_bounds__(256) void k_mach_gather(
    const int* __restrict__ mach_rs, const int* __restrict__ bucket_mach,
    const float* __restrict__ op_emb, float* __restrict__ mach_sum) {
    int m = blockIdx.x;
    int t = threadIdx.x;
    int wave = t >> 6, lane = t & 63;
    int h = (wave & 1) * 64 + lane;
    int pair = wave >> 1;
    int s0 = mach_rs[m], e0 = mach_rs[m + 1];
    float acc = 0.f;
    for (int base = s0 + (blockIdx.y * 2 + pair) * 64; base < e0; base += gridDim.y * 128) {
        int cnt = min(64, e0 - base);
        int idx = (lane < cnt) ? bucket_mach[base + lane] : 0;
        for (int j = 0; j < cnt; j += 4) {
            int i0 = __shfl(idx, j);
            int i1 = __shfl(idx, j + 1);
            int i2 = __shfl(idx, j + 2);
            int i3 = __shfl(idx, j + 3);
            float v0 = op_emb[(size_t)i0 * HDIM + h];
            float v1 = op_emb[(size_t)i1 * HDIM + h];
            float v2 = op_emb[(size_t)i2 * HDIM + h];
            float v3 = op_emb[(size_t)i3 * HDIM + h];
            acc += v0;
            if (j + 1 < cnt) acc += v1;
            if (j + 2 < cnt) acc += v2;
            if (j + 3 < cnt) acc += v3;
        }
    }
    atomicAdd(&mach_sum[m * HDIM + h], acc);
}

// ---------------- machine update: mean -> @Wc^T + bc -> +emb -> LN ----------------
__global__ __launch_bounds__(128) void k_mach_update(
    const float* __restrict__ mach_emb, const float* __restrict__ mach_sum,
    const int* __restrict__ mach_rs,
    const float* __restrict__ Wc, const float* __restrict__ bc,
    const float* __restrict__ g, const float* __restrict__ bt,
    float* __restrict__ dst) {
    __shared__ float row[HDIM];
    __shared__ float red[4];
    int m = blockIdx.x, t = threadIdx.x;
    int cnt = mach_rs[m + 1] - mach_rs[m];
    float sc = (cnt > 0) ? 1.f / (float)cnt : 0.f;
    row[t] = mach_sum[m * HDIM + t] * sc;
    __syncthreads();
    float dot = bc[t];
    const float* w = Wc + (size_t)t * HDIM;
#pragma unroll 8
    for (int k = 0; k < HDIM; ++k) dot += row[k] * w[k];
    float x = mach_emb[m * HDIM + t] + ((cnt > 0) ? dot : 0.f);
    float s = x, q = x * x;
#pragma unroll
    for (int o = 32; o; o >>= 1) { s += __shfl_xor(s, o); q += __shfl_xor(q, o); }
    int wv = t >> 6;
    if ((t & 63) == 0) { red[wv * 2] = s; red[wv * 2 + 1] = q; }
    __syncthreads();
    s = red[0] + red[2]; q = red[1] + red[3];
    float mu = s * (1.f / 128.f);
    float rstd = rsqrtf(fmaxf(q * (1.f / 128.f) - mu * mu, 0.f) + 1e-5f);
    dst[m * HDIM + t] = (x - mu) * rstd * g[t] + bt[t];
}

extern "C" void kernel_launch(void* const* d_in, const int* in_sizes, int n_in,
                              void* d_out, int out_size, void* d_ws, size_t ws_size,
                              hipStream_t stream) {
    const float* op_feat    = (const float*)d_in[0];
    const float* m_feat     = (const float*)d_in[1];
    const int*   prec_e     = (const int*)d_in[2];
    const int*   comp_e     = (const int*)d_in[3];
    const float* op_emb_W   = (const float*)d_in[4];
    const float* op_emb_b   = (const float*)d_in[5];
    const float* mach_emb_W = (const float*)d_in[6];
    const float* mach_emb_b = (const float*)d_in[7];
    const float* prec_W     = (const float*)d_in[8];
    const float* prec_b     = (const float*)d_in[9];
    const float* compat_W   = (const float*)d_in[10];
    const float* compat_b   = (const float*)d_in[11];
    const float* op_ln_g    = (const float*)d_in[12];
    const float* op_ln_b    = (const float*)d_in[13];
    const float* mach_ln_g  = (const float*)d_in[14];
    const float* mach_ln_b  = (const float*)d_in[15];
    float* out = (float*)d_out;

    const int M = NUM_OPS, NM = NUM_MACH;
    const int nprec = in_sizes[2] / 2;
    const int ncomp = in_sizes[3] / 2;
    const int E = ncomp / 2;   // bidirectional pairs: first half o2m, second half m2o (mirror)
    const int NT = nprec + E;

    float* ws = (float*)d_ws;
    size_t o = 0;
    float* op_emb   = ws + o; o += (size_t)M * HDIM;    // 51 MB
    unsigned short* Ab = (unsigned short*)(ws + o); o += (size_t)M * 128;  // 51 MB bf16 [M][256]
    unsigned short* Wb = (unsigned short*)(ws + o); o += 32768;            // 2 layers x [128][256] bf16
    float* mach_emb = ws + o; o += (size_t)NM * HDIM;
    float* mach_sum = ws + o; o += (size_t)NM * HDIM;
    int* ip = (int*)(ws + o);
    size_t io = 0;
    int* chist     = ip + io; io += NHIST;     // coarse blockhist [784][256]
    int* rs        = ip + io; io += NHIST;     // fine row starts (exclusive)
    int* cscan     = ip + io; io += NHIST;     // scanned coarse blockhist
    int* blockhist = ip + io; io += MHWORDS;
    int* moff      = ip + io; io += MHWORDS;
    int* mach_rs   = ip + io; io += NM + 8;
    int* partialA  = ip + io; io += 256;
    int* block_offA= ip + io; io += 256;
    int* partialB  = ip + io; io += 256;
    int* block_offB= ip + io; io += 256;
    int* flags     = ip + io; io += M;
    int* pairs     = ip + io; io += (size_t)NT;               // coarse-partitioned packed edges
    int* bucket_all  = ip + io; io += (size_t)NT;
    int* bucket_mach = ip + io; io += (size_t)E;

    // ---- CSR build: two-level counting sort (no global scattered atomics) ----
    k_chist<<<NBC, 256, 0, stream>>>(prec_e, nprec, comp_e, E, chist);
    k_mhist<<<NBM, 256, 0, stream>>>(comp_e, E, M, blockhist);
    k_blocksum<<<NBLK, 256, 0, stream>>>(chist, partialA);
    k_scanpart<<<1, 256, 0, stream>>>(partialA, NBLK, block_offA);
    k_scanwrite<<<NBLK, 256, 0, stream>>>(chist, block_offA, cscan, nullptr);
    k_blocksum<<<NBLK_M, 256, 0, stream>>>(blockhist, partialB);
    k_scanpart<<<1, 256, 0, stream>>>(partialB, NBLK_M, block_offB);
    k_scanwrite<<<NBLK_M, 256, 0, stream>>>(blockhist, block_offB, moff, nullptr);
    k_machrs<<<1, 256, 0, stream>>>(moff, mach_rs, E);
    k_cfill<<<NBC, 256, 0, stream>>>(prec_e, nprec, comp_e, E, M, cscan, pairs);
    k_fine<<<NCOARSE, 256, 0, stream>>>(cscan, pairs, NT, rs, bucket_all);
    k_fill_mach<<<NBM, 256, 0, stream>>>(comp_e, E, M, moff, bucket_mach);

    // ---- input embeddings + weight conversion ----
    k_embed<<<(M * HDIM + 255) / 256, 256, 0, stream>>>(op_feat, op_emb_W, op_emb_b, op_emb, M, 6);
    k_embed<<<(NM * HDIM + 255) / 256, 256, 0, stream>>>(m_feat, mach_emb_W, mach_emb_b, mach_emb, NM, 2);
    k_wconv<<<(2 * 128 * 256 + 255) / 256, 256, 0, stream>>>(prec_W, compat_W, Wb);

    for (int l = 0; l < 2; ++l) {
        int last = (l == 1);
        const float* bpl = prec_b   + (size_t)l * HDIM;
        const float* Wc  = compat_W + (size_t)l * HDIM * HDIM;
        const float* bcl = compat_b + (size_t)l * HDIM;

        hipMemsetAsync(mach_sum, 0, (size_t)NM * HDIM * sizeof(float), stream);

        // both aggregations read OLD op_emb / mach_emb
        k_agg_op<<<(M + 3) / 4, 256, 0, stream>>>(op_emb, mach_emb, rs, bucket_all, Ab, flags, M);
        k_mach_gather<<<dim3(NM, 4), 256, 0, stream>>>(mach_rs, bucket_mach, op_emb, mach_sum);

        // op update (overwrites op_emb after all reads of it)
        k_gemm_mfma<<<(M + 63) / 64, 256, 0, stream>>>(
            Ab, op_emb, Wb + (size_t)l * 128 * 256, bpl, bcl, flags,
            op_ln_g + (size_t)l * HDIM, op_ln_b + (size_t)l * HDIM,
            last ? out : op_emb, M);

        // machine update (overwrites mach_emb after k_agg_op read it)
        k_mach_update<<<NM, 128, 0, stream>>>(
            mach_emb, mach_sum, mach_rs, Wc, bcl,
            mach_ln_g + (size_t)l * HDIM, mach_ln_b + (size_t)l * HDIM,
            last ? (out + (size_t)M * HDIM) : mach_emb);
    }
}

// Round 2
// 583.232 us; speedup vs baseline: 1.4064x; 1.1815x over previous
//
#include <hip/hip_runtime.h>
#include <hip/hip_bf16.h>

#define NUM_OPS   100000
#define NUM_MACH  512
#define HDIM      128
#define P1        100352            // m2o key offset (98*1024)
#define NHIST     200704            // 196*1024 == 784*256 combined key space
#define NBLK      196               // hist scan blocks (1024 elems each)
#define NCOARSE   784               // coarse buckets (key >> 8)
#define NBC       256               // blocks for coarse hist/fill passes
#define NBM       256               // counting-sort blocks for machine buckets
#define MHWORDS   (NUM_MACH * NBM)  // 131072 = 128*1024
#define NBLK_M    128               // blockhist scan blocks

typedef short short8 __attribute__((ext_vector_type(8)));
typedef float floatx4 __attribute__((ext_vector_type(4)));

__device__ __forceinline__ unsigned short f2bf(float f) {
    unsigned u = __float_as_uint(f);
    unsigned r = (u + 0x7FFFu + ((u >> 16) & 1u)) >> 16;   // RNE
    return (unsigned short)r;
}
__device__ __forceinline__ float bf2f(unsigned short u) {
    return __uint_as_float(((unsigned)u) << 16);
}

// ---------------- embedding: out[r,h] = sum_f F[r,f]*W[h,f] + b[h] (+ bf16 mirror) ----------------
__global__ void k_embed(const float* __restrict__ F,
                        const float* __restrict__ W,
                        const float* __restrict__ b,
                        float* __restrict__ out,
                        unsigned short* __restrict__ outb, int M, int FD) {
    int idx = blockIdx.x * blockDim.x + threadIdx.x;
    if (idx >= M * HDIM) return;
    int r = idx >> 7, h = idx & 127;
    const float* f = F + (size_t)r * FD;
    const float* w = W + (size_t)h * FD;
    float s = b[h];
    for (int i = 0; i < FD; ++i) s += f[i] * w[i];
    out[idx] = s;
    if (outb) outb[idx] = f2bf(s);
}

// ---------------- weight convert: Wb[l][h][0:256] = bf16(Wp[l][h] || Wc[l][h]) ----------------
__global__ void k_wconv(const float* __restrict__ Wp, const float* __restrict__ Wc,
                        unsigned short* __restrict__ Wb) {
    int i = blockIdx.x * blockDim.x + threadIdx.x;
    if (i >= 2 * 128 * 256) return;
    int l = i >> 15, h = (i >> 8) & 127, k = i & 255;
    float v = (k < 128) ? Wp[(size_t)l * 16384 + h * 128 + k]
                        : Wc[(size_t)l * 16384 + h * 128 + (k - 128)];
    Wb[i] = f2bf(v);
}

// ---------------- coarse pass A: per-block LDS histograms over key>>8 ----------------
// key space: prec targets at [0,NUM_OPS), m2o targets at [P1, P1+NUM_OPS)
__global__ __launch_bounds__(256) void k_chist(const int* __restrict__ prec_e, int nprec,
                                               const int* __restrict__ comp_e, int E,
                                               int* __restrict__ blockhist) {
    __shared__ int h[NCOARSE];
    for (int i = threadIdx.x; i < NCOARSE; i += 256) h[i] = 0;
    __syncthreads();
    int NT = nprec + E;
    int ch = (NT + NBC - 1) / NBC;
    int i0 = blockIdx.x * ch, i1 = min(NT, i0 + ch);
    for (int i = i0 + threadIdx.x; i < i1; i += 256) {
        int key = (i < nprec) ? prec_e[nprec + i] : (P1 + comp_e[i - nprec]);
        atomicAdd(&h[key >> 8], 1);
    }
    __syncthreads();
    for (int i = threadIdx.x; i < NCOARSE; i += 256)
        blockhist[i * NBC + blockIdx.x] = h[i];
}

// ---------------- coarse pass B: place packed (val<<8 | key&255) via LDS cursors ----------------
__global__ __launch_bounds__(256) void k_cfill(const int* __restrict__ prec_e, int nprec,
                                               const int* __restrict__ comp_e, int E, int M,
                                               const int* __restrict__ scan,
                                               int* __restrict__ pairs) {
    __shared__ int cur[NCOARSE];
    for (int i = threadIdx.x; i < NCOARSE; i += 256) cur[i] = scan[i * NBC + blockIdx.x];
    __syncthreads();
    int NT = nprec + E;
    int ch = (NT + NBC - 1) / NBC;
    int i0 = blockIdx.x * ch, i1 = min(NT, i0 + ch);
    for (int i = i0 + threadIdx.x; i < i1; i += 256) {
        int key, val;
        if (i < nprec) { key = prec_e[nprec + i]; val = prec_e[i]; }
        else { int e = i - nprec; key = P1 + comp_e[e]; val = comp_e[E + e] - M; }
        int pos = atomicAdd(&cur[key >> 8], 1);
        pairs[pos] = (val << 8) | (key & 255);
    }
}

// ---------------- fine pass: per-coarse-bucket counting sort (256 keys, LDS) ----------------
// writes rs[key] for all 256 keys of the bucket + scatters values into bucket_all
__global__ __launch_bounds__(256) void k_fine(const int* __restrict__ scan,
                                              const int* __restrict__ pairs, int NT,
                                              int* __restrict__ rs,
                                              int* __restrict__ bucket_all) {
    __shared__ int hh[256];
    __shared__ int ex[256];
    __shared__ int cu[256];
    int b = blockIdx.x, t = threadIdx.x;
    int s = scan[b * NBC];
    int e = (b == NCOARSE - 1) ? NT : scan[(b + 1) * NBC];
    hh[t] = 0;
    __syncthreads();
    for (int i = s + t; i < e; i += 256) atomicAdd(&hh[pairs[i] & 255], 1);
    __syncthreads();
    int v = hh[t];
    ex[t] = v; __syncthreads();
    for (int o = 1; o < 256; o <<= 1) {
        int x = (t >= o) ? ex[t - o] : 0; __syncthreads();
        ex[t] += x; __syncthreads();
    }
    int start = s + ex[t] - v;      // exclusive offset for key b*256+t
    rs[b * 256 + t] = start;
    cu[t] = start;
    __syncthreads();
    for (int i = s + t; i < e; i += 256) {
        int p = pairs[i];
        int pos = atomicAdd(&cu[p & 255], 1);
        bucket_all[pos] = ((unsigned)p) >> 8;
    }
}

// ---------------- machine counting-sort pass A: per-block LDS histograms ----------------
__global__ __launch_bounds__(256) void k_mhist(const int* __restrict__ comp_e, int E, int M,
                                               int* __restrict__ blockhist) {
    __shared__ int h[NUM_MACH];
    for (int i = threadIdx.x; i < NUM_MACH; i += 256) h[i] = 0;
    __syncthreads();
    int blk = blockIdx.x;
    int ch = (E + NBM - 1) / NBM;
    int e0 = blk * ch, e1 = min(E, e0 + ch);
    for (int e = e0 + threadIdx.x; e < e1; e += 256)
        atomicAdd(&h[comp_e[E + e] - M], 1);
    __syncthreads();
    for (int i = threadIdx.x; i < NUM_MACH; i += 256)
        blockhist[i * NBM + blk] = h[i];
}

// ---------------- scan phase 1: per-block sums (1024 ints / block) ----------------
__global__ __launch_bounds__(256) void k_blocksum(const int* __restrict__ arr, int* __restrict__ partial) {
    __shared__ int sh[256];
    int b = blockIdx.x, t = threadIdx.x;
    int4 v = *(const int4*)(arr + b * 1024 + t * 4);
    sh[t] = v.x + v.y + v.z + v.w;
    __syncthreads();
    for (int o = 128; o; o >>= 1) { if (t < o) sh[t] += sh[t + o]; __syncthreads(); }
    if (!t) partial[b] = sh[0];
}

// ---------------- scan phase 2: exclusive scan of <=256 partials, single block ----------------
__global__ __launch_bounds__(256) void k_scanpart(const int* __restrict__ partial, int n,
                                                  int* __restrict__ block_off) {
    __shared__ int sh[256];
    int t = threadIdx.x;
    int v = (t < n) ? partial[t] : 0;
    sh[t] = v; __syncthreads();
    for (int o = 1; o < 256; o <<= 1) {
        int x = (t >= o) ? sh[t - o] : 0; __syncthreads();
        sh[t] += x; __syncthreads();
    }
    if (t < n) block_off[t] = sh[t] - v;
}

// ---------------- scan phase 3: write exclusive offsets (+ optional cursor copy) ----------------
__global__ __launch_bounds__(256) void k_scanwrite(const int* __restrict__ arr,
                                                   const int* __restrict__ block_off,
                                                   int* __restrict__ rs, int* __restrict__ cur) {
    __shared__ int sh[256];
    int b = blockIdx.x, t = threadIdx.x;
    int base_i = b * 1024 + t * 4;
    int4 v = *(const int4*)(arr + base_i);
    int tsum = v.x + v.y + v.z + v.w;
    sh[t] = tsum; __syncthreads();
    for (int o = 1; o < 256; o <<= 1) {
        int x = (t >= o) ? sh[t - o] : 0; __syncthreads();
        sh[t] += x; __syncthreads();
    }
    int off = block_off[b] + sh[t] - tsum;
    int4 r; r.x = off; r.y = off + v.x; r.z = off + v.x + v.y; r.w = off + v.x + v.y + v.z;
    *(int4*)(rs + base_i) = r;
    if (cur) *(int4*)(cur + base_i) = r;
}

// ---------------- extract machine row starts from scanned blockhist column 0 ----------------
__global__ void k_machrs(const int* __restrict__ moff, int* __restrict__ mach_rs, int E) {
    int t = threadIdx.x;
    for (int m = t; m < NUM_MACH; m += 256) mach_rs[m] = moff[m * NBM];
    if (t == 0) mach_rs[NUM_MACH] = E;
}

// ---------------- machine counting-sort pass B: placement via LDS cursors ----------------
__global__ __launch_bounds__(256) void k_fill_mach(const int* __restrict__ comp_e, int E, int M,
                                                   const int* __restrict__ moff,
                                                   int* __restrict__ bucket_mach) {
    __shared__ int cur[NUM_MACH];
    int blk = blockIdx.x;
    for (int i = threadIdx.x; i < NUM_MACH; i += 256) cur[i] = moff[i * NBM + blk];
    __syncthreads();
    int ch = (E + NBM - 1) / NBM;
    int e0 = blk * ch, e1 = min(E, e0 + ch);
    for (int e = e0 + threadIdx.x; e < e1; e += 256) {
        int m = comp_e[E + e] - M;
        int op = comp_e[e];
        int pos = atomicAdd(&cur[m], 1);
        bucket_mach[pos] = op;
    }
}

// ---------------- op aggregation: bf16 prec gather + f32 mach gather -> bf16 A ----------------
__global__ __launch_bounds__(256) void k_agg_op(
    const unsigned short* __restrict__ op_ebf, const float* __restrict__ mach_emb,
    const int* __restrict__ rs, const int* __restrict__ bucket_all,
    unsigned short* __restrict__ Ab, int* __restrict__ flags, int M) {
    int wave = threadIdx.x >> 6, lane = threadIdx.x & 63;
    int r = blockIdx.x * 4 + wave;
    if (r >= M) return;
    int h = lane * 2;

    float a0 = 0.f, a1 = 0.f;
    int s0 = rs[r], e0 = rs[r + 1];
    for (int base = s0; base < e0; base += 64) {
        int cnt = min(64, e0 - base);
        int idx = (lane < cnt) ? bucket_all[base + lane] : 0;
        for (int j = 0; j < cnt; j += 4) {
            int i0 = __shfl(idx, j);
            int i1 = __shfl(idx, j + 1);
            int i2 = __shfl(idx, j + 2);
            int i3 = __shfl(idx, j + 3);
            ushort2 v0 = *(const ushort2*)(op_ebf + (size_t)i0 * HDIM + h);
            ushort2 v1 = *(const ushort2*)(op_ebf + (size_t)i1 * HDIM + h);
            ushort2 v2 = *(const ushort2*)(op_ebf + (size_t)i2 * HDIM + h);
            ushort2 v3 = *(const ushort2*)(op_ebf + (size_t)i3 * HDIM + h);
            a0 += bf2f(v0.x); a1 += bf2f(v0.y);
            if (j + 1 < cnt) { a0 += bf2f(v1.x); a1 += bf2f(v1.y); }
            if (j + 2 < cnt) { a0 += bf2f(v2.x); a1 += bf2f(v2.y); }
            if (j + 3 < cnt) { a0 += bf2f(v3.x); a1 += bf2f(v3.y); }
        }
    }
    float pinv = 1.f / fmaxf((float)(e0 - s0), 1.f);

    float b0 = 0.f, b1 = 0.f;
    int s1 = rs[P1 + r], e1 = rs[P1 + r + 1];
    for (int base = s1; base < e1; base += 64) {
        int cnt = min(64, e1 - base);
        int idx = (lane < cnt) ? bucket_all[base + lane] : 0;
        for (int j = 0; j < cnt; j += 4) {
            int i0 = __shfl(idx, j);
            int i1 = __shfl(idx, j + 1);
            int i2 = __shfl(idx, j + 2);
            int i3 = __shfl(idx, j + 3);
            float2 v0 = *(const float2*)(mach_emb + (size_t)i0 * HDIM + h);
            float2 v1 = *(const float2*)(mach_emb + (size_t)i1 * HDIM + h);
            float2 v2 = *(const float2*)(mach_emb + (size_t)i2 * HDIM + h);
            float2 v3 = *(const float2*)(mach_emb + (size_t)i3 * HDIM + h);
            b0 += v0.x; b1 += v0.y;
            if (j + 1 < cnt) { b0 += v1.x; b1 += v1.y; }
            if (j + 2 < cnt) { b0 += v2.x; b1 += v2.y; }
            if (j + 3 < cnt) { b0 += v3.x; b1 += v3.y; }
        }
    }
    float cinv = 1.f / fmaxf((float)(e1 - s1), 1.f);

    ushort2 pa, pb;
    pa.x = f2bf(a0 * pinv); pa.y = f2bf(a1 * pinv);
    pb.x = f2bf(b0 * cinv); pb.y = f2bf(b1 * cinv);
    *(ushort2*)(Ab + (size_t)r * 256 + h)       = pa;
    *(ushort2*)(Ab + (size_t)r * 256 + 128 + h) = pb;
    if (lane == 0) flags[r] = (e0 > s0 ? 1 : 0) | (e1 > s1 ? 2 : 0);
}

// ---------------- MFMA GEMM + residual + bias-flags + LayerNorm (+ optional bf16 mirror) ------
// out[r] = LN(emb[r] + A[r,0:256]@Wb^T + fp*bp + fc*bc)
// A-operand layout: A[m=lane&15][k=quad*8+j]; C/D: row=quad*4+reg, col=lane&15.
__global__ __launch_bounds__(256) void k_gemm_mfma(
    const unsigned short* __restrict__ Ab, const float* __restrict__ emb,
    const unsigned short* __restrict__ Wb,
    const float* __restrict__ bp, const float* __restrict__ bc,
    const int* __restrict__ flags,
    const float* __restrict__ g, const float* __restrict__ bt,
    float* __restrict__ dst, unsigned short* __restrict__ dstb, int M) {
    int wave = threadIdx.x >> 6, lane = threadIdx.x & 63;
    int m0 = blockIdx.x * 64 + wave * 16;
    if (m0 >= M) return;
    int quad = lane >> 4, col = lane & 15;

    floatx4 acc[8];
#pragma unroll
    for (int t = 0; t < 8; ++t) acc[t] = (floatx4){0.f, 0.f, 0.f, 0.f};

    const short* Arow  = (const short*)(Ab + (size_t)(m0 + col) * 256);
    const short* Wbase = (const short*)Wb;

#pragma unroll
    for (int ks = 0; ks < 8; ++ks) {
        short8 a = *(const short8*)(Arow + ks * 32 + quad * 8);
#pragma unroll
        for (int t = 0; t < 8; ++t) {
            short8 b = *(const short8*)(Wbase + (size_t)(t * 16 + col) * 256 + ks * 32 + quad * 8);
            acc[t] = __builtin_amdgcn_mfma_f32_16x16x32_bf16(a, b, acc[t], 0, 0, 0);
        }
    }

    float bpv[8], bcv[8], gv[8], btv[8];
#pragma unroll
    for (int t = 0; t < 8; ++t) {
        int c = t * 16 + col;
        bpv[t] = bp[c]; bcv[t] = bc[c]; gv[t] = g[c]; btv[t] = bt[c];
    }
#pragma unroll
    for (int reg = 0; reg < 4; ++reg) {
        int r = m0 + quad * 4 + reg;
        int fl = flags[r];
        float fp = (fl & 1) ? 1.f : 0.f, fc = (fl & 2) ? 1.f : 0.f;
        float x[8]; float s = 0.f, q = 0.f;
#pragma unroll
        for (int t = 0; t < 8; ++t) {
            float v = acc[t][reg] + emb[(size_t)r * HDIM + t * 16 + col] + fp * bpv[t] + fc * bcv[t];
            x[t] = v; s += v; q += v * v;
        }
#pragma unroll
        for (int msk = 1; msk < 16; msk <<= 1) { s += __shfl_xor(s, msk); q += __shfl_xor(q, msk); }
        float mu = s * (1.f / 128.f);
        float rstd = rsqrtf(fmaxf(q * (1.f / 128.f) - mu * mu, 0.f) + 1e-5f);
#pragma unroll
        for (int t = 0; t < 8; ++t) {
            float y = (x[t] - mu) * rstd * gv[t] + btv[t];
            dst[(size_t)r * HDIM + t * 16 + col] = y;
            if (dstb) dstb[(size_t)r * HDIM + t * 16 + col] = f2bf(y);
        }
    }
}

// ---------------- machine gather (bf16 rows): wave owns 64-edge batch, full row ----------------
__global__ __launch_bounds__(256) void k_mach_gather(
    const int* __restrict__ mach_rs, const int* __restrict__ bucket_mach,
    const unsigned short* __restrict__ op_ebf, float* __restrict__ mach_sum) {
    int m = blockIdx.x;
    int t = threadIdx.x;
    int wave = t >> 6, lane = t & 63;
    int h = lane * 2;
    int s0 = mach_rs[m], e0 = mach_rs[m + 1];
    float a0 = 0.f, a1 = 0.f;
    for (int base = s0 + (blockIdx.y * 4 + wave) * 64; base < e0; base += gridDim.y * 256) {
        int cnt = min(64, e0 - base);
        int idx = (lane < cnt) ? bucket_mach[base + lane] : 0;
        for (int j = 0; j < cnt; j += 4) {
            int i0 = __shfl(idx, j);
            int i1 = __shfl(idx, j + 1);
            int i2 = __shfl(idx, j + 2);
            int i3 = __shfl(idx, j + 3);
            ushort2 v0 = *(const ushort2*)(op_ebf + (size_t)i0 * HDIM + h);
            ushort2 v1 = *(const ushort2*)(op_ebf + (size_t)i1 * HDIM + h);
            ushort2 v2 = *(const ushort2*)(op_ebf + (size_t)i2 * HDIM + h);
            ushort2 v3 = *(const ushort2*)(op_ebf + (size_t)i3 * HDIM + h);
            a0 += bf2f(v0.x); a1 += bf2f(v0.y);
            if (j + 1 < cnt) { a0 += bf2f(v1.x); a1 += bf2f(v1.y); }
            if (j + 2 < cnt) { a0 += bf2f(v2.x); a1 += bf2f(v2.y); }
            if (j + 3 < cnt) { a0 += bf2f(v3.x); a1 += bf2f(v3.y); }
        }
    }
    atomicAdd(&mach_sum[m * HDIM + h], a0);
    atomicAdd(&mach_sum[m * HDIM + h + 1], a1);
}

// ---------------- machine update: mean -> @Wc^T + bc -> +emb -> LN ----------------
__global__ __launch_bounds__(128) void k_mach_update(
    const float* __restrict__ mach_emb, const float* __restrict__ mach_sum,
    const int* __restrict__ mach_rs,
    const float* __restrict__ Wc, const float* __restrict__ bc,
    const float* __restrict__ g, const float* __restrict__ bt,
    float* __restrict__ dst) {
    __shared__ float row[HDIM];
    __shared__ float red[4];
    int m = blockIdx.x, t = threadIdx.x;
    int cnt = mach_rs[m + 1] - mach_rs[m];
    float sc = (cnt > 0) ? 1.f / (float)cnt : 0.f;
    row[t] = mach_sum[m * HDIM + t] * sc;
    __syncthreads();
    float dot = bc[t];
    const float* w = Wc + (size_t)t * HDIM;
#pragma unroll 8
    for (int k = 0; k < HDIM; ++k) dot += row[k] * w[k];
    float x = mach_emb[m * HDIM + t] + ((cnt > 0) ? dot : 0.f);
    float s = x, q = x * x;
#pragma unroll
    for (int o = 32; o; o >>= 1) { s += __shfl_xor(s, o); q += __shfl_xor(q, o); }
    int wv = t >> 6;
    if ((t & 63) == 0) { red[wv * 2] = s; red[wv * 2 + 1] = q; }
    __syncthreads();
    s = red[0] + red[2]; q = red[1] + red[3];
    float mu = s * (1.f / 128.f);
    float rstd = rsqrtf(fmaxf(q * (1.f / 128.f) - mu * mu, 0.f) + 1e-5f);
    dst[m * HDIM + t] = (x - mu) * rstd * g[t] + bt[t];
}

extern "C" void kernel_launch(void* const* d_in, const int* in_sizes, int n_in,
                              void* d_out, int out_size, void* d_ws, size_t ws_size,
                              hipStream_t stream) {
    const float* op_feat    = (const float*)d_in[0];
    const float* m_feat     = (const float*)d_in[1];
    const int*   prec_e     = (const int*)d_in[2];
    const int*   comp_e     = (const int*)d_in[3];
    const float* op_emb_W   = (const float*)d_in[4];
    const float* op_emb_b   = (const float*)d_in[5];
    const float* mach_emb_W = (const float*)d_in[6];
    const float* mach_emb_b = (const float*)d_in[7];
    const float* prec_W     = (const float*)d_in[8];
    const float* prec_b     = (const float*)d_in[9];
    const float* compat_W   = (const float*)d_in[10];
    const float* compat_b   = (const float*)d_in[11];
    const float* op_ln_g    = (const float*)d_in[12];
    const float* op_ln_b    = (const float*)d_in[13];
    const float* mach_ln_g  = (const float*)d_in[14];
    const float* mach_ln_b  = (const float*)d_in[15];
    float* out = (float*)d_out;

    const int M = NUM_OPS, NM = NUM_MACH;
    const int nprec = in_sizes[2] / 2;
    const int ncomp = in_sizes[3] / 2;
    const int E = ncomp / 2;   // bidirectional pairs: first half o2m, second half m2o (mirror)
    const int NT = nprec + E;

    float* ws = (float*)d_ws;
    size_t o = 0;
    float* op_emb   = ws + o; o += (size_t)M * HDIM;    // 51 MB
    unsigned short* op_ebf = (unsigned short*)(ws + o); o += (size_t)M * 64;   // 25.6 MB bf16 mirror
    unsigned short* Ab = (unsigned short*)(ws + o); o += (size_t)M * 128;  // 51 MB bf16 [M][256]
    unsigned short* Wb = (unsigned short*)(ws + o); o += 32768;            // 2 layers x [128][256] bf16
    float* mach_emb = ws + o; o += (size_t)NM * HDIM;
    float* mach_sum = ws + o; o += (size_t)NM * HDIM;
    int* ip = (int*)(ws + o);
    size_t io = 0;
    int* chist     = ip + io; io += NHIST;     // coarse blockhist [784][256]
    int* rs        = ip + io; io += NHIST;     // fine row starts (exclusive)
    int* cscan     = ip + io; io += NHIST;     // scanned coarse blockhist
    int* blockhist = ip + io; io += MHWORDS;
    int* moff      = ip + io; io += MHWORDS;
    int* mach_rs   = ip + io; io += NM + 8;
    int* partialA  = ip + io; io += 256;
    int* block_offA= ip + io; io += 256;
    int* partialB  = ip + io; io += 256;
    int* block_offB= ip + io; io += 256;
    int* flags     = ip + io; io += M;
    int* pairs     = ip + io; io += (size_t)NT;               // coarse-partitioned packed edges
    int* bucket_all  = ip + io; io += (size_t)NT;
    int* bucket_mach = ip + io; io += (size_t)E;

    // ---- CSR build: two-level counting sort (no global scattered atomics) ----
    k_chist<<<NBC, 256, 0, stream>>>(prec_e, nprec, comp_e, E, chist);
    k_mhist<<<NBM, 256, 0, stream>>>(comp_e, E, M, blockhist);
    k_blocksum<<<NBLK, 256, 0, stream>>>(chist, partialA);
    k_scanpart<<<1, 256, 0, stream>>>(partialA, NBLK, block_offA);
    k_scanwrite<<<NBLK, 256, 0, stream>>>(chist, block_offA, cscan, nullptr);
    k_blocksum<<<NBLK_M, 256, 0, stream>>>(blockhist, partialB);
    k_scanpart<<<1, 256, 0, stream>>>(partialB, NBLK_M, block_offB);
    k_scanwrite<<<NBLK_M, 256, 0, stream>>>(blockhist, block_offB, moff, nullptr);
    k_machrs<<<1, 256, 0, stream>>>(moff, mach_rs, E);
    k_cfill<<<NBC, 256, 0, stream>>>(prec_e, nprec, comp_e, E, M, cscan, pairs);
    k_fine<<<NCOARSE, 256, 0, stream>>>(cscan, pairs, NT, rs, bucket_all);
    k_fill_mach<<<NBM, 256, 0, stream>>>(comp_e, E, M, moff, bucket_mach);

    // ---- input embeddings + weight conversion ----
    k_embed<<<(M * HDIM + 255) / 256, 256, 0, stream>>>(op_feat, op_emb_W, op_emb_b, op_emb, op_ebf, M, 6);
    k_embed<<<(NM * HDIM + 255) / 256, 256, 0, stream>>>(m_feat, mach_emb_W, mach_emb_b, mach_emb, nullptr, NM, 2);
    k_wconv<<<(2 * 128 * 256 + 255) / 256, 256, 0, stream>>>(prec_W, compat_W, Wb);

    for (int l = 0; l < 2; ++l) {
        int last = (l == 1);
        const float* bpl = prec_b   + (size_t)l * HDIM;
        const float* Wc  = compat_W + (size_t)l * HDIM * HDIM;
        const float* bcl = compat_b + (size_t)l * HDIM;

        hipMemsetAsync(mach_sum, 0, (size_t)NM * HDIM * sizeof(float), stream);

        // both aggregations read OLD op_ebf / mach_emb
        k_agg_op<<<(M + 3) / 4, 256, 0, stream>>>(op_ebf, mach_emb, rs, bucket_all, Ab, flags, M);
        k_mach_gather<<<dim3(NM, 4), 256, 0, stream>>>(mach_rs, bucket_mach, op_ebf, mach_sum);

        // op update (overwrites op_emb/op_ebf after all reads of them)
        k_gemm_mfma<<<(M + 63) / 64, 256, 0, stream>>>(
            Ab, op_emb, Wb + (size_t)l * 128 * 256, bpl, bcl, flags,
            op_ln_g + (size_t)l * HDIM, op_ln_b + (size_t)l * HDIM,
            last ? out : op_emb, last ? nullptr : op_ebf, M);

        // machine update (overwrites mach_emb after k_agg_op read it)
        k_mach_update<<<NM, 128, 0, stream>>>(
            mach_emb, mach_sum, mach_rs, Wc, bcl,
            mach_ln_g + (size_t)l * HDIM, mach_ln_b + (size_t)l * HDIM,
            last ? (out + (size_t)M * HDIM) : mach_emb);
    }
}